// Round 5
// baseline (200.880 us; speedup 1.0000x reference)
//
#include <hip/hip_runtime.h>

#define H_ 1024
#define W_ 1024
#define B_ 4
#define CIN 16
#define COUT 16
#define TH 16
#define TW 64
#define ROWS 18       // TH+2
#define COLS 66       // TW+2

#define LRELU 0.2f
#define GAIN_ 1.4142135623730951f
#define EPS_ 1e-8f

typedef __attribute__((ext_vector_type(8))) short bf16x8;
typedef __attribute__((ext_vector_type(4))) float f32x4;

static __device__ __forceinline__ unsigned short f32_to_bf16(float f) {
    unsigned int u = __float_as_uint(f);
    unsigned int r = u + 0x7FFF + ((u >> 16) & 1);   // RNE
    return (unsigned short)(r >> 16);
}

static __device__ __forceinline__ float f4c(const float4& v, int px) {
    return px == 0 ? v.x : px == 1 ? v.y : px == 2 ? v.z : v.w;
}

// ---------------- setup 1: s[b,i] = w @ (fcw.T * 512^-0.5) + bias; copy w to out ----
__global__ __launch_bounds__(256) void k_setup1(
    const float* __restrict__ w, const float* __restrict__ fcw,
    const float* __restrict__ fcb, float* __restrict__ s_out,
    float* __restrict__ w_copy_out)
{
    __shared__ float part[256];
    const int tid = threadIdx.x;
    const int bi = tid >> 2;   // 0..63 -> (b,i)
    const int q  = tid & 3;
    const int b = bi >> 4, i = bi & 15;
    const float* wr = w + b * 512 + q * 128;
    const float* fr = fcw + i * 512 + q * 128;
    float acc = 0.f;
    #pragma unroll 8
    for (int k = 0; k < 128; ++k) acc += wr[k] * fr[k];
    part[tid] = acc;
    __syncthreads();
    if (tid < 64) {
        float v = part[tid*4] + part[tid*4+1] + part[tid*4+2] + part[tid*4+3];
        s_out[tid] = v * 0.04419417382415922f /* 512^-0.5 */ + fcb[tid & 15];
    }
    for (int e = tid; e < B_ * 512; e += 256) w_copy_out[e] = w[e];
}

// ---------------- setup 2: d[b,o], W_eff -> pre-swizzled bf16 A-fragments ----------
// afrag layout: [b][t=0..4][lane=0..63][j=0..7], A[o=lane&15][k=g*8+j],
// k -> (tap = 2t + (g>>1), i = (g&1)*8 + j); tap 9 zeroed.
__global__ __launch_bounds__(256) void k_setup2(
    const float* __restrict__ s_in, const float* __restrict__ convw,
    unsigned short* __restrict__ afrag)
{
    const int b = blockIdx.x;
    const int tid = threadIdx.x;
    __shared__ float s_sh[16];
    __shared__ float d_sh[16];
    __shared__ float wc_sh[COUT * CIN * 9];
    __shared__ float part[256];

    if (tid < 16) s_sh[tid] = s_in[b * 16 + tid];
    for (int e = tid; e < COUT * CIN * 9; e += 256)
        wc_sh[e] = convw[e] * (1.0f / 12.0f);   // (16*9)^-0.5
    __syncthreads();

    const int o = tid >> 4, i = tid & 15;
    const float si = s_sh[i];
    float acc = 0.f;
    #pragma unroll
    for (int tap = 0; tap < 9; ++tap) {
        float v = wc_sh[(o * 16 + i) * 9 + tap] * si;
        acc += v * v;
    }
    part[tid] = acc;
    __syncthreads();
    if (tid < 16) {
        float sum = EPS_;
        #pragma unroll
        for (int j = 0; j < 16; ++j) sum += part[tid * 16 + j];
        d_sh[tid] = rsqrtf(sum);
    }
    __syncthreads();

    for (int e = tid; e < 5 * 64 * 8; e += 256) {
        int t = e >> 9;
        int lane = (e >> 3) & 63;
        int j = e & 7;
        int oo = lane & 15, g = lane >> 4;
        int ii = (g & 1) * 8 + j;
        int tap = 2 * t + (g >> 1);
        float v = 0.f;
        if (tap < 9) v = wc_sh[(oo * 16 + ii) * 9 + tap] * s_sh[ii] * d_sh[oo];
        afrag[(size_t)b * (5 * 64 * 8) + e] = f32_to_bf16(v);
    }
}

// ---------------- main conv: big-tile implicit GEMM, TH=16 x TW=64, 512 thr --------
// Single LDS buffer (38 KB -> 4 blocks/CU @ 512 thr if VGPR<=64), one barrier.
// Staging: 576 interior units (row,hh,cg) + 72 edge units; phase A = units 0..511
// on all tids, phase B = remaining 136 units on tids 0..135.
__global__ __launch_bounds__(512, 8) void k_conv(
    const float* __restrict__ x, const float* __restrict__ noise,
    const float* __restrict__ conv_bias, const float* __restrict__ sn_ptr,
    const unsigned short* __restrict__ afrag, float* __restrict__ y)
{
    __shared__ unsigned short tile[2][ROWS][COLS][8]; // 38016 B

    const int tid = threadIdx.x;
    const int bt = blockIdx.z;
    const int h0 = blockIdx.y * TH;
    const int w0 = blockIdx.x * TW;
    const float sn = sn_ptr[0];
    const float* xb = x + (size_t)bt * CIN * H_ * W_;
    float* yb = y + (size_t)bt * COUT * H_ * W_;
    const float* nb = noise + (size_t)bt * H_ * W_;

    const int lane  = tid & 63;
    const int wid   = tid >> 6;          // 0..7
    const int p     = lane & 15;
    const int g     = lane >> 4;
    const int ghalf = g >> 1;
    const int chalf = g & 1;

    // ---- phase A: units u = tid (rows 0..15) ----
    {
        const int row = tid >> 5;
        const int hh  = (tid >> 4) & 1;
        const int cg  = tid & 15;
        const int gh  = h0 - 1 + row;
        const bool ok = (gh >= 0) && (gh < H_);
        const float* base = xb + ((size_t)(8 * hh) * H_ + gh) * W_ + (w0 + 4 * cg);
        float4 v[8];
        #pragma unroll
        for (int c = 0; c < 8; ++c) {
            v[c] = make_float4(0.f, 0.f, 0.f, 0.f);
            if (ok) v[c] = *reinterpret_cast<const float4*>(base + (size_t)c * H_ * W_);
        }
        #pragma unroll
        for (int px = 0; px < 4; ++px) {
            bf16x8 pk;
            #pragma unroll
            for (int c = 0; c < 8; ++c) pk[c] = (short)f32_to_bf16(f4c(v[c], px));
            *reinterpret_cast<bf16x8*>(&tile[hh][row][1 + 4 * cg + px][0]) = pk;
        }
    }

    // ---- phase B: units 512..647 on tids 0..135 ----
    if (tid < 64) {
        // interior rows 16..17
        const int row = 16 + (tid >> 5);
        const int hh  = (tid >> 4) & 1;
        const int cg  = tid & 15;
        const int gh  = h0 - 1 + row;
        const bool ok = (gh >= 0) && (gh < H_);
        const float* base = xb + ((size_t)(8 * hh) * H_ + gh) * W_ + (w0 + 4 * cg);
        float4 v[8];
        #pragma unroll
        for (int c = 0; c < 8; ++c) {
            v[c] = make_float4(0.f, 0.f, 0.f, 0.f);
            if (ok) v[c] = *reinterpret_cast<const float4*>(base + (size_t)c * H_ * W_);
        }
        #pragma unroll
        for (int px = 0; px < 4; ++px) {
            bf16x8 pk;
            #pragma unroll
            for (int c = 0; c < 8; ++c) pk[c] = (short)f32_to_bf16(f4c(v[c], px));
            *reinterpret_cast<bf16x8*>(&tile[hh][row][1 + 4 * cg + px][0]) = pk;
        }
    } else if (tid < 136) {
        // edge columns: 72 units (row 0..17, side, hh)
        const int e    = tid - 64;
        const int row  = e >> 2;
        const int side = (e >> 1) & 1;
        const int hh   = e & 1;
        const int col  = side * (COLS - 1);
        const int gh   = h0 - 1 + row;
        const int gw   = w0 - 1 + col;
        const bool ok  = (gh >= 0) && (gh < H_) && (gw >= 0) && (gw < W_);
        bf16x8 pk;
        #pragma unroll
        for (int c = 0; c < 8; ++c) {
            float v = ok ? xb[((size_t)(8 * hh + c) * H_ + gh) * W_ + gw] : 0.f;
            pk[c] = (short)f32_to_bf16(v);
        }
        *reinterpret_cast<bf16x8*>(&tile[hh][row][col][0]) = pk;
    }

    // ---- A-fragments + bias (issued after staging; overlap barrier wait) ----
    bf16x8 a[5];
    {
        const bf16x8* ap = reinterpret_cast<const bf16x8*>(afrag + (size_t)bt * 5 * 64 * 8);
        #pragma unroll
        for (int t = 0; t < 5; ++t) a[t] = ap[t * 64 + lane];
    }
    float bias_j[4];
    #pragma unroll
    for (int j = 0; j < 4; ++j) bias_j[j] = conv_bias[g * 4 + j];

    int lroff[5], lcoff[5];
    #pragma unroll
    for (int t = 0; t < 5; ++t) {
        int tap = 2 * t + ghalf;
        if (tap > 8) tap = 8;        // padded slot; A is zero there
        lroff[t] = tap / 3;
        lcoff[t] = tap % 3;
    }

    __syncthreads();

    #pragma unroll
    for (int rr = 0; rr < 2; ++rr) {
        const int oh = wid * 2 + rr;        // 0..15
        const int gh = h0 + oh;
        #pragma unroll
        for (int gc = 0; gc < 4; ++gc) {
            const int ow = gc * 16;
            f32x4 acc = {0.f, 0.f, 0.f, 0.f};
            #pragma unroll
            for (int tt = 0; tt < 5; ++tt) {
                const bf16x8 bv = *reinterpret_cast<const bf16x8*>(
                    &tile[chalf][oh + lroff[tt]][ow + p + lcoff[tt]][0]);
                acc = __builtin_amdgcn_mfma_f32_16x16x32_bf16(a[tt], bv, acc, 0, 0, 0);
            }
            const int gw = w0 + ow + p;
            const float noi = nb[(size_t)gh * W_ + gw] * sn;
            #pragma unroll
            for (int j = 0; j < 4; ++j) {
                float vv = acc[j] + bias_j[j] + noi;
                vv = (vv >= 0.f) ? vv : (LRELU * vv);
                yb[((size_t)(g * 4 + j) * H_ + gh) * W_ + gw] = vv * GAIN_;
            }
        }
    }
}

extern "C" void kernel_launch(void* const* d_in, const int* in_sizes, int n_in,
                              void* d_out, int out_size, void* d_ws, size_t ws_size,
                              hipStream_t stream)
{
    const float* w     = (const float*)d_in[0];
    const float* x     = (const float*)d_in[1];
    const float* noise = (const float*)d_in[2];
    const float* fcw   = (const float*)d_in[3];
    const float* fcb   = (const float*)d_in[4];
    const float* convw = (const float*)d_in[5];
    const float* convb = (const float*)d_in[6];
    const float* sn    = (const float*)d_in[7];

    float* out = (float*)d_out;
    float* ws_s = (float*)d_ws;                                        // 64 f32
    unsigned short* ws_afrag = (unsigned short*)((char*)d_ws + 256);   // 10240 u16

    k_setup1<<<1, 256, 0, stream>>>(w, fcw, fcb, ws_s, out);
    k_setup2<<<B_, 256, 0, stream>>>(ws_s, convw, ws_afrag);
    dim3 grid(W_ / TW, H_ / TH, B_);
    k_conv<<<grid, 512, 0, stream>>>(x, noise, convb, sn, ws_afrag, out + 2048);
}

// Round 6
// 179.776 us; speedup vs baseline: 1.1174x; 1.1174x over previous
//
#include <hip/hip_runtime.h>

#define H_ 1024
#define W_ 1024
#define B_ 4
#define CIN 16
#define COUT 16
#define TH 4
#define TW 128
#define ROWS 6        // TH+2
#define COLS 130      // TW+2

#define LRELU 0.2f
#define GAIN_ 1.4142135623730951f
#define EPS_ 1e-8f

typedef __attribute__((ext_vector_type(8))) short bf16x8;
typedef __attribute__((ext_vector_type(4))) float f32x4;

static __device__ __forceinline__ unsigned short f32_to_bf16(float f) {
    unsigned int u = __float_as_uint(f);
    unsigned int r = u + 0x7FFF + ((u >> 16) & 1);   // RNE
    return (unsigned short)(r >> 16);
}

static __device__ __forceinline__ float f4c(const float4& v, int px) {
    return px == 0 ? v.x : px == 1 ? v.y : px == 2 ? v.z : v.w;
}

// ---------------- setup 1: s[b,i] = w @ (fcw.T * 512^-0.5) + bias; copy w to out ----
__global__ __launch_bounds__(256) void k_setup1(
    const float* __restrict__ w, const float* __restrict__ fcw,
    const float* __restrict__ fcb, float* __restrict__ s_out,
    float* __restrict__ w_copy_out)
{
    __shared__ float part[256];
    const int tid = threadIdx.x;
    const int bi = tid >> 2;   // 0..63 -> (b,i)
    const int q  = tid & 3;
    const int b = bi >> 4, i = bi & 15;
    const float* wr = w + b * 512 + q * 128;
    const float* fr = fcw + i * 512 + q * 128;
    float acc = 0.f;
    #pragma unroll 8
    for (int k = 0; k < 128; ++k) acc += wr[k] * fr[k];
    part[tid] = acc;
    __syncthreads();
    if (tid < 64) {
        float v = part[tid*4] + part[tid*4+1] + part[tid*4+2] + part[tid*4+3];
        s_out[tid] = v * 0.04419417382415922f /* 512^-0.5 */ + fcb[tid & 15];
    }
    for (int e = tid; e < B_ * 512; e += 256) w_copy_out[e] = w[e];
}

// ---------------- setup 2: d[b,o], W_eff -> pre-swizzled bf16 A-fragments ----------
// afrag layout: [b][t=0..4][lane=0..63][j=0..7], A[o=lane&15][k=g*8+j],
// k -> (tap = 2t + (g>>1), i = (g&1)*8 + j); tap 9 zeroed.
__global__ __launch_bounds__(256) void k_setup2(
    const float* __restrict__ s_in, const float* __restrict__ convw,
    unsigned short* __restrict__ afrag)
{
    const int b = blockIdx.x;
    const int tid = threadIdx.x;
    __shared__ float s_sh[16];
    __shared__ float d_sh[16];
    __shared__ float wc_sh[COUT * CIN * 9];
    __shared__ float part[256];

    if (tid < 16) s_sh[tid] = s_in[b * 16 + tid];
    for (int e = tid; e < COUT * CIN * 9; e += 256)
        wc_sh[e] = convw[e] * (1.0f / 12.0f);   // (16*9)^-0.5
    __syncthreads();

    const int o = tid >> 4, i = tid & 15;
    const float si = s_sh[i];
    float acc = 0.f;
    #pragma unroll
    for (int tap = 0; tap < 9; ++tap) {
        float v = wc_sh[(o * 16 + i) * 9 + tap] * si;
        acc += v * v;
    }
    part[tid] = acc;
    __syncthreads();
    if (tid < 16) {
        float sum = EPS_;
        #pragma unroll
        for (int j = 0; j < 16; ++j) sum += part[tid * 16 + j];
        d_sh[tid] = rsqrtf(sum);
    }
    __syncthreads();

    for (int e = tid; e < 5 * 64 * 8; e += 256) {
        int t = e >> 9;
        int lane = (e >> 3) & 63;
        int j = e & 7;
        int oo = lane & 15, g = lane >> 4;
        int ii = (g & 1) * 8 + j;
        int tap = 2 * t + (g >> 1);
        float v = 0.f;
        if (tap < 9) v = wc_sh[(oo * 16 + ii) * 9 + tap] * s_sh[ii] * d_sh[oo];
        afrag[(size_t)b * (5 * 64 * 8) + e] = f32_to_bf16(v);
    }
}

// ---------------- main conv: wide-chunk tile TH=4 x TW=128, 256 thr ----------------
// 520B contiguous per channel-row read, 512B per channel-row write (DRAM-locality
// probe). Single 25KB LDS buffer, one barrier, r2-style two-slice staging.
// Interior units u=(row,hh,cg): 6*2*32 = 384 -> slice A = tid, slice B = 256+tid
// (tid<128). Edge units 24 on tid 128..151.
__global__ __launch_bounds__(256, 4) void k_conv(
    const float* __restrict__ x, const float* __restrict__ noise,
    const float* __restrict__ conv_bias, const float* __restrict__ sn_ptr,
    const unsigned short* __restrict__ afrag, float* __restrict__ y)
{
    __shared__ unsigned short tile[2][ROWS][COLS][8]; // 24960 B

    const int tid = threadIdx.x;
    const int bt = blockIdx.z;
    const int h0 = blockIdx.y * TH;
    const int w0 = blockIdx.x * TW;
    const float sn = sn_ptr[0];
    const float* xb = x + (size_t)bt * CIN * H_ * W_;
    float* yb = y + (size_t)bt * COUT * H_ * W_;
    const float* nb = noise + (size_t)bt * H_ * W_;

    const int lane  = tid & 63;
    const int wid   = tid >> 6;          // 0..3
    const int p     = lane & 15;
    const int g     = lane >> 4;
    const int ghalf = g >> 1;
    const int chalf = g & 1;

    // ---- slice A: unit u = tid (rows 0..3 and part of row 4) ----
    {
        const int row = tid >> 6;        // 0..3
        const int hh  = (tid >> 5) & 1;
        const int cg  = tid & 31;
        const int gh  = h0 - 1 + row;
        const bool ok = (gh >= 0) && (gh < H_);
        const float* base = xb + ((size_t)(8 * hh) * H_ + gh) * W_ + (w0 + 4 * cg);
        float4 v[8];
        #pragma unroll
        for (int c = 0; c < 8; ++c) {
            v[c] = make_float4(0.f, 0.f, 0.f, 0.f);
            if (ok) v[c] = *reinterpret_cast<const float4*>(base + (size_t)c * H_ * W_);
        }
        #pragma unroll
        for (int px = 0; px < 4; ++px) {
            bf16x8 pk;
            #pragma unroll
            for (int c = 0; c < 8; ++c) pk[c] = (short)f32_to_bf16(f4c(v[c], px));
            *reinterpret_cast<bf16x8*>(&tile[hh][row][1 + 4 * cg + px][0]) = pk;
        }
    }

    // ---- slice B: unit u = 256 + tid for tid<128 (rows 4..5); edges on 128..151 ----
    if (tid < 128) {
        const int u   = 256 + tid;
        const int row = u >> 6;          // 4..5
        const int hh  = (u >> 5) & 1;
        const int cg  = u & 31;
        const int gh  = h0 - 1 + row;
        const bool ok = (gh >= 0) && (gh < H_);
        const float* base = xb + ((size_t)(8 * hh) * H_ + gh) * W_ + (w0 + 4 * cg);
        float4 v[8];
        #pragma unroll
        for (int c = 0; c < 8; ++c) {
            v[c] = make_float4(0.f, 0.f, 0.f, 0.f);
            if (ok) v[c] = *reinterpret_cast<const float4*>(base + (size_t)c * H_ * W_);
        }
        #pragma unroll
        for (int px = 0; px < 4; ++px) {
            bf16x8 pk;
            #pragma unroll
            for (int c = 0; c < 8; ++c) pk[c] = (short)f32_to_bf16(f4c(v[c], px));
            *reinterpret_cast<bf16x8*>(&tile[hh][row][1 + 4 * cg + px][0]) = pk;
        }
    } else if (tid < 152) {
        const int e    = tid - 128;
        const int row  = e >> 2;         // 0..5
        const int side = (e >> 1) & 1;
        const int hh   = e & 1;
        const int col  = side * (COLS - 1);
        const int gh   = h0 - 1 + row;
        const int gw   = w0 - 1 + side * (COLS - 1);
        const bool ok  = (gh >= 0) && (gh < H_) && (gw >= 0) && (gw < W_);
        bf16x8 pk;
        #pragma unroll
        for (int c = 0; c < 8; ++c) {
            float v = ok ? xb[((size_t)(8 * hh + c) * H_ + gh) * W_ + gw] : 0.f;
            pk[c] = (short)f32_to_bf16(v);
        }
        *reinterpret_cast<bf16x8*>(&tile[hh][row][col][0]) = pk;
    }

    // ---- A-fragments + bias ----
    bf16x8 a[5];
    {
        const bf16x8* ap = reinterpret_cast<const bf16x8*>(afrag + (size_t)bt * 5 * 64 * 8);
        #pragma unroll
        for (int t = 0; t < 5; ++t) a[t] = ap[t * 64 + lane];
    }
    float bias_j[4];
    #pragma unroll
    for (int j = 0; j < 4; ++j) bias_j[j] = conv_bias[g * 4 + j];

    int lroff[5], lcoff[5];
    #pragma unroll
    for (int t = 0; t < 5; ++t) {
        int tap = 2 * t + ghalf;
        if (tap > 8) tap = 8;        // padded slot; A is zero there
        lroff[t] = tap / 3;
        lcoff[t] = tap % 3;
    }

    __syncthreads();

    const int oh = wid;                  // 0..3
    const int gh = h0 + oh;
    #pragma unroll
    for (int gc = 0; gc < 8; ++gc) {
        const int ow = gc * 16;
        f32x4 acc = {0.f, 0.f, 0.f, 0.f};
        #pragma unroll
        for (int tt = 0; tt < 5; ++tt) {
            const bf16x8 bv = *reinterpret_cast<const bf16x8*>(
                &tile[chalf][oh + lroff[tt]][ow + p + lcoff[tt]][0]);
            acc = __builtin_amdgcn_mfma_f32_16x16x32_bf16(a[tt], bv, acc, 0, 0, 0);
        }
        const int gw = w0 + ow + p;
        const float noi = nb[(size_t)gh * W_ + gw] * sn;
        #pragma unroll
        for (int j = 0; j < 4; ++j) {
            float vv = acc[j] + bias_j[j] + noi;
            vv = (vv >= 0.f) ? vv : (LRELU * vv);
            yb[((size_t)(g * 4 + j) * H_ + gh) * W_ + gw] = vv * GAIN_;
        }
    }
}

extern "C" void kernel_launch(void* const* d_in, const int* in_sizes, int n_in,
                              void* d_out, int out_size, void* d_ws, size_t ws_size,
                              hipStream_t stream)
{
    const float* w     = (const float*)d_in[0];
    const float* x     = (const float*)d_in[1];
    const float* noise = (const float*)d_in[2];
    const float* fcw   = (const float*)d_in[3];
    const float* fcb   = (const float*)d_in[4];
    const float* convw = (const float*)d_in[5];
    const float* convb = (const float*)d_in[6];
    const float* sn    = (const float*)d_in[7];

    float* out = (float*)d_out;
    float* ws_s = (float*)d_ws;                                        // 64 f32
    unsigned short* ws_afrag = (unsigned short*)((char*)d_ws + 256);   // 10240 u16

    k_setup1<<<1, 256, 0, stream>>>(w, fcw, fcb, ws_s, out);
    k_setup2<<<B_, 256, 0, stream>>>(ws_s, convw, ws_afrag);
    dim3 grid(W_ / TW, H_ / TH, B_);
    k_conv<<<grid, 256, 0, stream>>>(x, noise, convb, sn, ws_afrag, out + 2048);
}

// Round 7
// 173.046 us; speedup vs baseline: 1.1608x; 1.0389x over previous
//
#include <hip/hip_runtime.h>

#define H_ 1024
#define W_ 1024
#define B_ 4
#define CIN 16
#define COUT 16
#define TH 8
#define TW 64
#define NT 8          // vertical tiles per persistent block
#define ROWS 10       // TH+2
#define COLS 66       // TW+2

#define LRELU 0.2f
#define GAIN_ 1.4142135623730951f
#define EPS_ 1e-8f

typedef __attribute__((ext_vector_type(8))) short bf16x8;
typedef __attribute__((ext_vector_type(4))) float f32x4;

static __device__ __forceinline__ unsigned short f32_to_bf16(float f) {
    unsigned int u = __float_as_uint(f);
    unsigned int r = u + 0x7FFF + ((u >> 16) & 1);   // RNE
    return (unsigned short)(r >> 16);
}

static __device__ __forceinline__ float f4c(const float4& v, int px) {
    return px == 0 ? v.x : px == 1 ? v.y : px == 2 ? v.z : v.w;
}

// ---------------- setup 1: s[b,i] = w @ (fcw.T * 512^-0.5) + bias; copy w to out ----
__global__ __launch_bounds__(256) void k_setup1(
    const float* __restrict__ w, const float* __restrict__ fcw,
    const float* __restrict__ fcb, float* __restrict__ s_out,
    float* __restrict__ w_copy_out)
{
    __shared__ float part[256];
    const int tid = threadIdx.x;
    const int bi = tid >> 2;   // 0..63 -> (b,i)
    const int q  = tid & 3;
    const int b = bi >> 4, i = bi & 15;
    const float* wr = w + b * 512 + q * 128;
    const float* fr = fcw + i * 512 + q * 128;
    float acc = 0.f;
    #pragma unroll 8
    for (int k = 0; k < 128; ++k) acc += wr[k] * fr[k];
    part[tid] = acc;
    __syncthreads();
    if (tid < 64) {
        float v = part[tid*4] + part[tid*4+1] + part[tid*4+2] + part[tid*4+3];
        s_out[tid] = v * 0.04419417382415922f /* 512^-0.5 */ + fcb[tid & 15];
    }
    for (int e = tid; e < B_ * 512; e += 256) w_copy_out[e] = w[e];
}

// ---------------- setup 2: d[b,o], W_eff -> pre-swizzled bf16 A-fragments ----------
// afrag layout: [b][t=0..4][lane=0..63][j=0..7], A[o=lane&15][k=g*8+j],
// k -> (tap = 2t + (g>>1), i = (g&1)*8 + j); tap 9 zeroed.
__global__ __launch_bounds__(256) void k_setup2(
    const float* __restrict__ s_in, const float* __restrict__ convw,
    unsigned short* __restrict__ afrag)
{
    const int b = blockIdx.x;
    const int tid = threadIdx.x;
    __shared__ float s_sh[16];
    __shared__ float d_sh[16];
    __shared__ float wc_sh[COUT * CIN * 9];
    __shared__ float part[256];

    if (tid < 16) s_sh[tid] = s_in[b * 16 + tid];
    for (int e = tid; e < COUT * CIN * 9; e += 256)
        wc_sh[e] = convw[e] * (1.0f / 12.0f);   // (16*9)^-0.5
    __syncthreads();

    const int o = tid >> 4, i = tid & 15;
    const float si = s_sh[i];
    float acc = 0.f;
    #pragma unroll
    for (int tap = 0; tap < 9; ++tap) {
        float v = wc_sh[(o * 16 + i) * 9 + tap] * si;
        acc += v * v;
    }
    part[tid] = acc;
    __syncthreads();
    if (tid < 16) {
        float sum = EPS_;
        #pragma unroll
        for (int j = 0; j < 16; ++j) sum += part[tid * 16 + j];
        d_sh[tid] = rsqrtf(sum);
    }
    __syncthreads();

    for (int e = tid; e < 5 * 64 * 8; e += 256) {
        int t = e >> 9;
        int lane = (e >> 3) & 63;
        int j = e & 7;
        int oo = lane & 15, g = lane >> 4;
        int ii = (g & 1) * 8 + j;
        int tap = 2 * t + (g >> 1);
        float v = 0.f;
        if (tap < 9) v = wc_sh[(oo * 16 + ii) * 9 + tap] * s_sh[ii] * d_sh[oo];
        afrag[(size_t)b * (5 * 64 * 8) + e] = f32_to_bf16(v);
    }
}

// ---------------- main conv: persistent blocks, cross-tile prefetch ----------------
// TW=64 x TH=8 tiles, NT=8 per block, single 21KB LDS buffer, 2 barriers/tile:
//   [barrier] ldswrite(t) [barrier] issue-load(t+1) compute+store(t)
// Loads for t+1 are in flight during all of compute(t) -> read duty cycle ~1.
// grid = 1024 blocks = exactly 4/CU resident (one wave, no tail).
__global__ __launch_bounds__(256) void k_conv(
    const float* __restrict__ x, const float* __restrict__ noise,
    const float* __restrict__ conv_bias, const float* __restrict__ sn_ptr,
    const unsigned short* __restrict__ afrag, float* __restrict__ y)
{
    __shared__ unsigned short tile[2][ROWS][COLS][8]; // 21120 B

    const int tid = threadIdx.x;
    const int bt = blockIdx.z;
    const int h0s = blockIdx.y * (TH * NT);
    const int w0 = blockIdx.x * TW;
    const float sn = sn_ptr[0];
    const float* xb = x + (size_t)bt * CIN * H_ * W_;
    float* yb = y + (size_t)bt * COUT * H_ * W_;
    const float* nb = noise + (size_t)bt * H_ * W_;

    const int lane  = tid & 63;
    const int wid   = tid >> 6;
    const int p     = lane & 15;
    const int g     = lane >> 4;
    const int ghalf = g >> 1;
    const int chalf = g & 1;

    // staging decomposition (r4-proven, 84 VGPR):
    // unit A: all 256 tids -> rows 0..7;  unit B: tid<64 -> rows 8..9;
    // edges: tid 64..103 (40 units: 10 rows x 2 sides x 2 hh)
    const int rowA = tid >> 5, subA = tid & 31, hhA = subA >> 4, cgA = subA & 15;
    const int rowB = 8 + (tid >> 5);
    const bool hasB = (tid < 64);
    const bool hasE = (tid >= 64) && (tid < 104);
    const int e_  = tid - 64;
    const int rowE = e_ >> 2, sideE = (e_ >> 1) & 1, hhE = e_ & 1;

    float4 vA[8], vB[8];
    float  ev[8];

    auto stage_load = [&](int t) {
        const int gh0 = h0s + TH * t - 1;
        {
            const int gh = gh0 + rowA;
            const bool ok = (gh >= 0) && (gh < H_);
            const float* base = xb + ((size_t)(8 * hhA) * H_ + gh) * W_ + (w0 + 4 * cgA);
            #pragma unroll
            for (int c = 0; c < 8; ++c) {
                vA[c] = make_float4(0.f, 0.f, 0.f, 0.f);
                if (ok) vA[c] = *reinterpret_cast<const float4*>(base + (size_t)c * H_ * W_);
            }
        }
        if (hasB) {
            const int gh = gh0 + rowB;
            const bool ok = (gh >= 0) && (gh < H_);
            const float* base = xb + ((size_t)(8 * hhA) * H_ + gh) * W_ + (w0 + 4 * cgA);
            #pragma unroll
            for (int c = 0; c < 8; ++c) {
                vB[c] = make_float4(0.f, 0.f, 0.f, 0.f);
                if (ok) vB[c] = *reinterpret_cast<const float4*>(base + (size_t)c * H_ * W_);
            }
        } else if (hasE) {
            const int gh = gh0 + rowE;
            const int gw = w0 - 1 + sideE * (COLS - 1);
            const bool ok = (gh >= 0) && (gh < H_) && (gw >= 0) && (gw < W_);
            #pragma unroll
            for (int c = 0; c < 8; ++c)
                ev[c] = ok ? xb[((size_t)(8 * hhE + c) * H_ + gh) * W_ + gw] : 0.f;
        }
    };

    auto stage_write = [&]() {
        #pragma unroll
        for (int px = 0; px < 4; ++px) {
            bf16x8 pk;
            #pragma unroll
            for (int c = 0; c < 8; ++c) pk[c] = (short)f32_to_bf16(f4c(vA[c], px));
            *reinterpret_cast<bf16x8*>(&tile[hhA][rowA][1 + 4 * cgA + px][0]) = pk;
        }
        if (hasB) {
            #pragma unroll
            for (int px = 0; px < 4; ++px) {
                bf16x8 pk;
                #pragma unroll
                for (int c = 0; c < 8; ++c) pk[c] = (short)f32_to_bf16(f4c(vB[c], px));
                *reinterpret_cast<bf16x8*>(&tile[hhA][rowB][1 + 4 * cgA + px][0]) = pk;
            }
        } else if (hasE) {
            bf16x8 pk;
            #pragma unroll
            for (int c = 0; c < 8; ++c) pk[c] = (short)f32_to_bf16(ev[c]);
            *reinterpret_cast<bf16x8*>(&tile[hhE][rowE][sideE * (COLS - 1)][0]) = pk;
        }
    };

    // A-fragments + bias
    bf16x8 a[5];
    {
        const bf16x8* ap = reinterpret_cast<const bf16x8*>(afrag + (size_t)bt * 5 * 64 * 8);
        #pragma unroll
        for (int t = 0; t < 5; ++t) a[t] = ap[t * 64 + lane];
    }
    float bias_j[4];
    #pragma unroll
    for (int j = 0; j < 4; ++j) bias_j[j] = conv_bias[g * 4 + j];

    int lroff[5], lcoff[5];
    #pragma unroll
    for (int t = 0; t < 5; ++t) {
        int tap = 2 * t + ghalf;
        if (tap > 8) tap = 8;        // padded slot; A is zero there
        lroff[t] = tap / 3;
        lcoff[t] = tap % 3;
    }

    auto compute = [&](int t) {
        #pragma unroll
        for (int rr = 0; rr < 2; ++rr) {
            const int oh = wid * 2 + rr;
            const int gh = h0s + TH * t + oh;
            #pragma unroll
            for (int gc = 0; gc < 4; ++gc) {
                const int ow = gc * 16;
                f32x4 acc = {0.f, 0.f, 0.f, 0.f};
                #pragma unroll
                for (int tt = 0; tt < 5; ++tt) {
                    const bf16x8 bv = *reinterpret_cast<const bf16x8*>(
                        &tile[chalf][oh + lroff[tt]][ow + p + lcoff[tt]][0]);
                    acc = __builtin_amdgcn_mfma_f32_16x16x32_bf16(a[tt], bv, acc, 0, 0, 0);
                }
                const int gw = w0 + ow + p;
                const float noi = nb[(size_t)gh * W_ + gw] * sn;
                #pragma unroll
                for (int j = 0; j < 4; ++j) {
                    float vv = acc[j] + bias_j[j] + noi;
                    vv = (vv >= 0.f) ? vv : (LRELU * vv);
                    yb[((size_t)(g * 4 + j) * H_ + gh) * W_ + gw] = vv * GAIN_;
                }
            }
        }
    };

    // ---- persistent pipeline ----
    stage_load(0);
    for (int t = 0; t < NT; ++t) {
        if (t > 0) __syncthreads();      // readers of tile t-1 done
        stage_write();                    // waits vmcnt for load(t) internally
        __syncthreads();                  // tile t ready
        if (t + 1 < NT) stage_load(t + 1);  // in flight across compute(t)
        compute(t);
    }
}

extern "C" void kernel_launch(void* const* d_in, const int* in_sizes, int n_in,
                              void* d_out, int out_size, void* d_ws, size_t ws_size,
                              hipStream_t stream)
{
    const float* w     = (const float*)d_in[0];
    const float* x     = (const float*)d_in[1];
    const float* noise = (const float*)d_in[2];
    const float* fcw   = (const float*)d_in[3];
    const float* fcb   = (const float*)d_in[4];
    const float* convw = (const float*)d_in[5];
    const float* convb = (const float*)d_in[6];
    const float* sn    = (const float*)d_in[7];

    float* out = (float*)d_out;
    float* ws_s = (float*)d_ws;                                        // 64 f32
    unsigned short* ws_afrag = (unsigned short*)((char*)d_ws + 256);   // 10240 u16

    k_setup1<<<1, 256, 0, stream>>>(w, fcw, fcb, ws_s, out);
    k_setup2<<<B_, 256, 0, stream>>>(ws_s, convw, ws_afrag);
    dim3 grid(W_ / TW, H_ / (TH * NT), B_);
    k_conv<<<grid, 256, 0, stream>>>(x, noise, convb, sn, ws_afrag, out + 2048);
}

// Round 8
// 172.726 us; speedup vs baseline: 1.1630x; 1.0019x over previous
//
#include <hip/hip_runtime.h>

#define H_ 1024
#define W_ 1024
#define B_ 4
#define CIN 16
#define COUT 16
#define TH 8
#define TW 64
#define NT 8          // vertical tiles per persistent block
#define ROWS 10       // TH+2
#define COLS 66       // TW+2

#define LRELU 0.2f
#define GAIN_ 1.4142135623730951f
#define EPS_ 1e-8f

// Barrier with LDS-only drain: does NOT wait vmcnt, so prefetch loads and
// output stores stay in flight across it (hipcc's __syncthreads drains vmcnt(0)).
#define BAR_LGKM()                                                      \
    do {                                                                \
        __builtin_amdgcn_sched_barrier(0);                              \
        asm volatile("s_waitcnt lgkmcnt(0)\n\ts_barrier" ::: "memory"); \
        __builtin_amdgcn_sched_barrier(0);                              \
    } while (0)

typedef __attribute__((ext_vector_type(8))) short bf16x8;
typedef __attribute__((ext_vector_type(4))) float f32x4;

static __device__ __forceinline__ unsigned short f32_to_bf16(float f) {
    unsigned int u = __float_as_uint(f);
    unsigned int r = u + 0x7FFF + ((u >> 16) & 1);   // RNE
    return (unsigned short)(r >> 16);
}

static __device__ __forceinline__ float f4c(const float4& v, int px) {
    return px == 0 ? v.x : px == 1 ? v.y : px == 2 ? v.z : v.w;
}

// ---------------- setup 1: s[b,i] = w @ (fcw.T * 512^-0.5) + bias; copy w to out ----
__global__ __launch_bounds__(256) void k_setup1(
    const float* __restrict__ w, const float* __restrict__ fcw,
    const float* __restrict__ fcb, float* __restrict__ s_out,
    float* __restrict__ w_copy_out)
{
    __shared__ float part[256];
    const int tid = threadIdx.x;
    const int bi = tid >> 2;   // 0..63 -> (b,i)
    const int q  = tid & 3;
    const int b = bi >> 4, i = bi & 15;
    const float* wr = w + b * 512 + q * 128;
    const float* fr = fcw + i * 512 + q * 128;
    float acc = 0.f;
    #pragma unroll 8
    for (int k = 0; k < 128; ++k) acc += wr[k] * fr[k];
    part[tid] = acc;
    __syncthreads();
    if (tid < 64) {
        float v = part[tid*4] + part[tid*4+1] + part[tid*4+2] + part[tid*4+3];
        s_out[tid] = v * 0.04419417382415922f /* 512^-0.5 */ + fcb[tid & 15];
    }
    for (int e = tid; e < B_ * 512; e += 256) w_copy_out[e] = w[e];
}

// ---------------- setup 2: d[b,o], W_eff -> pre-swizzled bf16 A-fragments ----------
// afrag layout: [b][t=0..4][lane=0..63][j=0..7], A[o=lane&15][k=g*8+j],
// k -> (tap = 2t + (g>>1), i = (g&1)*8 + j); tap 9 zeroed.
__global__ __launch_bounds__(256) void k_setup2(
    const float* __restrict__ s_in, const float* __restrict__ convw,
    unsigned short* __restrict__ afrag)
{
    const int b = blockIdx.x;
    const int tid = threadIdx.x;
    __shared__ float s_sh[16];
    __shared__ float d_sh[16];
    __shared__ float wc_sh[COUT * CIN * 9];
    __shared__ float part[256];

    if (tid < 16) s_sh[tid] = s_in[b * 16 + tid];
    for (int e = tid; e < COUT * CIN * 9; e += 256)
        wc_sh[e] = convw[e] * (1.0f / 12.0f);   // (16*9)^-0.5
    __syncthreads();

    const int o = tid >> 4, i = tid & 15;
    const float si = s_sh[i];
    float acc = 0.f;
    #pragma unroll
    for (int tap = 0; tap < 9; ++tap) {
        float v = wc_sh[(o * 16 + i) * 9 + tap] * si;
        acc += v * v;
    }
    part[tid] = acc;
    __syncthreads();
    if (tid < 16) {
        float sum = EPS_;
        #pragma unroll
        for (int j = 0; j < 16; ++j) sum += part[tid * 16 + j];
        d_sh[tid] = rsqrtf(sum);
    }
    __syncthreads();

    for (int e = tid; e < 5 * 64 * 8; e += 256) {
        int t = e >> 9;
        int lane = (e >> 3) & 63;
        int j = e & 7;
        int oo = lane & 15, g = lane >> 4;
        int ii = (g & 1) * 8 + j;
        int tap = 2 * t + (g >> 1);
        float v = 0.f;
        if (tap < 9) v = wc_sh[(oo * 16 + ii) * 9 + tap] * s_sh[ii] * d_sh[oo];
        afrag[(size_t)b * (5 * 64 * 8) + e] = f32_to_bf16(v);
    }
}

// ---------------- main conv: persistent blocks, cross-tile prefetch ----------------
// Identical to round-7 kernel EXCEPT: the two per-tile __syncthreads are replaced
// by lgkmcnt-only barriers, so the compiler's vmcnt(0) barrier-drain no longer
// serializes prefetch loads and output stores per tile.
__global__ __launch_bounds__(256) void k_conv(
    const float* __restrict__ x, const float* __restrict__ noise,
    const float* __restrict__ conv_bias, const float* __restrict__ sn_ptr,
    const unsigned short* __restrict__ afrag, float* __restrict__ y)
{
    __shared__ unsigned short tile[2][ROWS][COLS][8]; // 21120 B

    const int tid = threadIdx.x;
    const int bt = blockIdx.z;
    const int h0s = blockIdx.y * (TH * NT);
    const int w0 = blockIdx.x * TW;
    const float sn = sn_ptr[0];
    const float* xb = x + (size_t)bt * CIN * H_ * W_;
    float* yb = y + (size_t)bt * COUT * H_ * W_;
    const float* nb = noise + (size_t)bt * H_ * W_;

    const int lane  = tid & 63;
    const int wid   = tid >> 6;
    const int p     = lane & 15;
    const int g     = lane >> 4;
    const int ghalf = g >> 1;
    const int chalf = g & 1;

    // staging decomposition:
    // unit A: all 256 tids -> rows 0..7;  unit B: tid<64 -> rows 8..9;
    // edges: tid 64..103 (40 units: 10 rows x 2 sides x 2 hh)
    const int rowA = tid >> 5, subA = tid & 31, hhA = subA >> 4, cgA = subA & 15;
    const int rowB = 8 + (tid >> 5);
    const bool hasB = (tid < 64);
    const bool hasE = (tid >= 64) && (tid < 104);
    const int e_  = tid - 64;
    const int rowE = e_ >> 2, sideE = (e_ >> 1) & 1, hhE = e_ & 1;

    float4 vA[8], vB[8];
    float  ev[8];

    auto stage_load = [&](int t) {
        const int gh0 = h0s + TH * t - 1;
        {
            const int gh = gh0 + rowA;
            const bool ok = (gh >= 0) && (gh < H_);
            const float* base = xb + ((size_t)(8 * hhA) * H_ + gh) * W_ + (w0 + 4 * cgA);
            #pragma unroll
            for (int c = 0; c < 8; ++c) {
                vA[c] = make_float4(0.f, 0.f, 0.f, 0.f);
                if (ok) vA[c] = *reinterpret_cast<const float4*>(base + (size_t)c * H_ * W_);
            }
        }
        if (hasB) {
            const int gh = gh0 + rowB;
            const bool ok = (gh >= 0) && (gh < H_);
            const float* base = xb + ((size_t)(8 * hhA) * H_ + gh) * W_ + (w0 + 4 * cgA);
            #pragma unroll
            for (int c = 0; c < 8; ++c) {
                vB[c] = make_float4(0.f, 0.f, 0.f, 0.f);
                if (ok) vB[c] = *reinterpret_cast<const float4*>(base + (size_t)c * H_ * W_);
            }
        } else if (hasE) {
            const int gh = gh0 + rowE;
            const int gw = w0 - 1 + sideE * (COLS - 1);
            const bool ok = (gh >= 0) && (gh < H_) && (gw >= 0) && (gw < W_);
            #pragma unroll
            for (int c = 0; c < 8; ++c)
                ev[c] = ok ? xb[((size_t)(8 * hhE + c) * H_ + gh) * W_ + gw] : 0.f;
        }
    };

    auto stage_write = [&]() {
        #pragma unroll
        for (int px = 0; px < 4; ++px) {
            bf16x8 pk;
            #pragma unroll
            for (int c = 0; c < 8; ++c) pk[c] = (short)f32_to_bf16(f4c(vA[c], px));
            *reinterpret_cast<bf16x8*>(&tile[hhA][rowA][1 + 4 * cgA + px][0]) = pk;
        }
        if (hasB) {
            #pragma unroll
            for (int px = 0; px < 4; ++px) {
                bf16x8 pk;
                #pragma unroll
                for (int c = 0; c < 8; ++c) pk[c] = (short)f32_to_bf16(f4c(vB[c], px));
                *reinterpret_cast<bf16x8*>(&tile[hhA][rowB][1 + 4 * cgA + px][0]) = pk;
            }
        } else if (hasE) {
            bf16x8 pk;
            #pragma unroll
            for (int c = 0; c < 8; ++c) pk[c] = (short)f32_to_bf16(ev[c]);
            *reinterpret_cast<bf16x8*>(&tile[hhE][rowE][sideE * (COLS - 1)][0]) = pk;
        }
    };

    // A-fragments + bias
    bf16x8 a[5];
    {
        const bf16x8* ap = reinterpret_cast<const bf16x8*>(afrag + (size_t)bt * 5 * 64 * 8);
        #pragma unroll
        for (int t = 0; t < 5; ++t) a[t] = ap[t * 64 + lane];
    }
    float bias_j[4];
    #pragma unroll
    for (int j = 0; j < 4; ++j) bias_j[j] = conv_bias[g * 4 + j];

    int lroff[5], lcoff[5];
    #pragma unroll
    for (int t = 0; t < 5; ++t) {
        int tap = 2 * t + ghalf;
        if (tap > 8) tap = 8;        // padded slot; A is zero there
        lroff[t] = tap / 3;
        lcoff[t] = tap % 3;
    }

    auto compute = [&](int t) {
        #pragma unroll
        for (int rr = 0; rr < 2; ++rr) {
            const int oh = wid * 2 + rr;
            const int gh = h0s + TH * t + oh;
            #pragma unroll
            for (int gc = 0; gc < 4; ++gc) {
                const int ow = gc * 16;
                f32x4 acc = {0.f, 0.f, 0.f, 0.f};
                #pragma unroll
                for (int tt = 0; tt < 5; ++tt) {
                    const bf16x8 bv = *reinterpret_cast<const bf16x8*>(
                        &tile[chalf][oh + lroff[tt]][ow + p + lcoff[tt]][0]);
                    acc = __builtin_amdgcn_mfma_f32_16x16x32_bf16(a[tt], bv, acc, 0, 0, 0);
                }
                const int gw = w0 + ow + p;
                const float noi = nb[(size_t)gh * W_ + gw] * sn;
                #pragma unroll
                for (int j = 0; j < 4; ++j) {
                    float vv = acc[j] + bias_j[j] + noi;
                    vv = (vv >= 0.f) ? vv : (LRELU * vv);
                    yb[((size_t)(g * 4 + j) * H_ + gh) * W_ + gw] = vv * GAIN_;
                }
            }
        }
    };

    // ---- persistent pipeline (lgkm-only barriers; vmem stays in flight) ----
    stage_load(0);
    for (int t = 0; t < NT; ++t) {
        if (t > 0) BAR_LGKM();           // readers of tile t-1 done (LDS WAR)
        stage_write();                    // compiler waits exact vmcnt for load(t)
        BAR_LGKM();                       // tile t visible (LDS RAW)
        if (t + 1 < NT) stage_load(t + 1);  // in flight across compute(t)
        compute(t);
    }
}

extern "C" void kernel_launch(void* const* d_in, const int* in_sizes, int n_in,
                              void* d_out, int out_size, void* d_ws, size_t ws_size,
                              hipStream_t stream)
{
    const float* w     = (const float*)d_in[0];
    const float* x     = (const float*)d_in[1];
    const float* noise = (const float*)d_in[2];
    const float* fcw   = (const float*)d_in[3];
    const float* fcb   = (const float*)d_in[4];
    const float* convw = (const float*)d_in[5];
    const float* convb = (const float*)d_in[6];
    const float* sn    = (const float*)d_in[7];

    float* out = (float*)d_out;
    float* ws_s = (float*)d_ws;                                        // 64 f32
    unsigned short* ws_afrag = (unsigned short*)((char*)d_ws + 256);   // 10240 u16

    k_setup1<<<1, 256, 0, stream>>>(w, fcw, fcb, ws_s, out);
    k_setup2<<<B_, 256, 0, stream>>>(ws_s, convw, ws_afrag);
    dim3 grid(W_ / TW, H_ / (TH * NT), B_);
    k_conv<<<grid, 256, 0, stream>>>(x, noise, convb, sn, ws_afrag, out + 2048);
}

// Round 9
// 167.591 us; speedup vs baseline: 1.1986x; 1.0306x over previous
//
#include <hip/hip_runtime.h>

#define H_ 1024
#define W_ 1024
#define B_ 4
#define CIN 16
#define COUT 16
#define TH 8
#define TW 64
#define NT 16         // vertical tiles per persistent block (strip = 128 rows)
#define ROWS 10       // TH+2
#define COLS_U 74     // swizzled 16B-units per row: max u = 65 + (65>>3) = 73

#define LRELU 0.2f
#define GAIN_ 1.4142135623730951f
#define EPS_ 1e-8f

// LDS-only barrier (no vmcnt drain): prefetch loads/stores stay in flight.
#define BAR_LGKM()                                                      \
    do {                                                                \
        __builtin_amdgcn_sched_barrier(0);                              \
        asm volatile("s_waitcnt lgkmcnt(0)\n\ts_barrier" ::: "memory"); \
        __builtin_amdgcn_sched_barrier(0);                              \
    } while (0)

typedef __attribute__((ext_vector_type(8))) short bf16x8;
typedef __attribute__((ext_vector_type(16))) float f32x16;

static __device__ __forceinline__ unsigned short f32_to_bf16(float f) {
    unsigned int u = __float_as_uint(f);
    unsigned int r = u + 0x7FFF + ((u >> 16) & 1);   // RNE
    return (unsigned short)(r >> 16);
}

static __device__ __forceinline__ float f4c(const float4& v, int px) {
    return px == 0 ? v.x : px == 1 ? v.y : px == 2 ? v.z : v.w;
}

static __device__ __forceinline__ int swz(int c) { return c + (c >> 3); }

// ---------------- setup 1: s[b,i] = w @ (fcw.T * 512^-0.5) + bias; copy w to out ----
__global__ __launch_bounds__(256) void k_setup1(
    const float* __restrict__ w, const float* __restrict__ fcw,
    const float* __restrict__ fcb, float* __restrict__ s_out,
    float* __restrict__ w_copy_out)
{
    __shared__ float part[256];
    const int tid = threadIdx.x;
    const int bi = tid >> 2;   // 0..63 -> (b,i)
    const int q  = tid & 3;
    const int b = bi >> 4, i = bi & 15;
    const float* wr = w + b * 512 + q * 128;
    const float* fr = fcw + i * 512 + q * 128;
    float acc = 0.f;
    #pragma unroll 8
    for (int k = 0; k < 128; ++k) acc += wr[k] * fr[k];
    part[tid] = acc;
    __syncthreads();
    if (tid < 64) {
        float v = part[tid*4] + part[tid*4+1] + part[tid*4+2] + part[tid*4+3];
        s_out[tid] = v * 0.04419417382415922f /* 512^-0.5 */ + fcb[tid & 15];
    }
    for (int e = tid; e < B_ * 512; e += 256) w_copy_out[e] = w[e];
}

// ---------------- setup 2: d[b,o], W_eff -> 32x32x16 A-fragments (P/Q packed) -------
// frag f = 0..5: f<3 -> P(C=f): m-half R=0 -> tap C, R=1 -> tap 3+C
//               f>=3 -> Q(C=f-3): R=0 -> tap 6+C, R=1 -> zero
// A layout (32x32x16): lane l holds A[m=l&31][k=8*(l>>5)+j], j=0..7.
// m = R*16 + o  (R=(l>>4)&1, o=l&15), k = input channel i.
__global__ __launch_bounds__(256) void k_setup2(
    const float* __restrict__ s_in, const float* __restrict__ convw,
    unsigned short* __restrict__ afrag)
{
    const int b = blockIdx.x;
    const int tid = threadIdx.x;
    __shared__ float s_sh[16];
    __shared__ float d_sh[16];
    __shared__ float wc_sh[COUT * CIN * 9];
    __shared__ float part[256];

    if (tid < 16) s_sh[tid] = s_in[b * 16 + tid];
    for (int e = tid; e < COUT * CIN * 9; e += 256)
        wc_sh[e] = convw[e] * (1.0f / 12.0f);   // (16*9)^-0.5
    __syncthreads();

    const int o = tid >> 4, i = tid & 15;
    const float si = s_sh[i];
    float acc = 0.f;
    #pragma unroll
    for (int tap = 0; tap < 9; ++tap) {
        float v = wc_sh[(o * 16 + i) * 9 + tap] * si;
        acc += v * v;
    }
    part[tid] = acc;
    __syncthreads();
    if (tid < 16) {
        float sum = EPS_;
        #pragma unroll
        for (int j = 0; j < 16; ++j) sum += part[tid * 16 + j];
        d_sh[tid] = rsqrtf(sum);
    }
    __syncthreads();

    for (int e = tid; e < 6 * 64 * 8; e += 256) {
        const int f    = e >> 9;         // 0..5
        const int lane = (e >> 3) & 63;
        const int j    = e & 7;
        const int C    = (f < 3) ? f : (f - 3);
        const bool isQ = (f >= 3);
        const int oo = lane & 15;
        const int R  = (lane >> 4) & 1;
        const int ii = 8 * (lane >> 5) + j;
        int tap;
        if (!isQ) tap = 3 * R + C;                 // rows 0,1
        else      tap = (R == 0) ? (6 + C) : -1;   // row 2 / zero pad
        float v = 0.f;
        if (tap >= 0) v = wc_sh[(oo * 16 + ii) * 9 + tap] * s_sh[ii] * d_sh[oo];
        afrag[(size_t)b * (6 * 64 * 8) + e] = f32_to_bf16(v);
    }
}

// ---------------- main conv: 32x32x16 M-packed implicit GEMM -----------------------
// 320 threads: waves 0..3 compute (slice s=w&1 rows 4s..4s+3, group g=w>>1 px 32g..),
// wave 4 = staging-only. Interior staging: unit = tid (10 rows x 2 chalf x 16 cg).
// Per wave-tile: 6-row sweep, 3 b128 reads + <=6 MFMAs per row, rolling chains:
//   out[r] = C_r.h0 + C_{r+1}.h1   (h0 = acc regs 0..7, h1 = regs 8..15)
__global__ __launch_bounds__(320) void k_conv(
    const float* __restrict__ x, const float* __restrict__ noise,
    const float* __restrict__ conv_bias, const float* __restrict__ sn_ptr,
    const unsigned short* __restrict__ afrag, float* __restrict__ y)
{
    __shared__ unsigned short tile[2][ROWS][COLS_U][8]; // 23680 B

    const int tid = threadIdx.x;
    const int bt = blockIdx.z;
    const int h0s = blockIdx.y * (TH * NT);
    const int w0 = blockIdx.x * TW;
    const float sn = sn_ptr[0];
    const float* xb = x + (size_t)bt * CIN * H_ * W_;
    float* yb = y + (size_t)bt * COUT * H_ * W_;
    const float* nb = noise + (size_t)bt * H_ * W_;

    const int lane = tid & 63;
    const int wid  = tid >> 6;           // 0..4

    // ---- staging roles ----
    const int rowS = tid >> 5;           // 0..9 (all 320 threads)
    const int subS = tid & 31;
    const int hhS  = subS >> 4;
    const int cgS  = subS & 15;
    const bool hasE = (tid >= 256) && (tid < 296);
    const int e_   = tid - 256;
    const int rowE = e_ >> 2, sideE = (e_ >> 1) & 1, hhE = e_ & 1;

    float4 vS[8];
    float  ev[8];

    auto stage_load = [&](int t) {
        const int gh0 = h0s + TH * t - 1;
        {
            const int gh = gh0 + rowS;
            const bool ok = (gh >= 0) && (gh < H_);
            const float* base = xb + ((size_t)(8 * hhS) * H_ + gh) * W_ + (w0 + 4 * cgS);
            #pragma unroll
            for (int c = 0; c < 8; ++c) {
                vS[c] = make_float4(0.f, 0.f, 0.f, 0.f);
                if (ok) vS[c] = *reinterpret_cast<const float4*>(base + (size_t)c * H_ * W_);
            }
        }
        if (hasE) {
            const int gh = gh0 + rowE;
            const int gw = w0 - 1 + sideE * 65;
            const bool ok = (gh >= 0) && (gh < H_) && (gw >= 0) && (gw < W_);
            #pragma unroll
            for (int c = 0; c < 8; ++c)
                ev[c] = ok ? xb[((size_t)(8 * hhE + c) * H_ + gh) * W_ + gw] : 0.f;
        }
    };

    auto stage_write = [&]() {
        #pragma unroll
        for (int px = 0; px < 4; ++px) {
            bf16x8 pk;
            #pragma unroll
            for (int c = 0; c < 8; ++c) pk[c] = (short)f32_to_bf16(f4c(vS[c], px));
            const int u = swz(1 + 4 * cgS + px);
            *reinterpret_cast<bf16x8*>(&tile[hhS][rowS][u][0]) = pk;
        }
        if (hasE) {
            bf16x8 pk;
            #pragma unroll
            for (int c = 0; c < 8; ++c) pk[c] = (short)f32_to_bf16(ev[c]);
            const int u = sideE ? swz(65) : 0;
            *reinterpret_cast<bf16x8*>(&tile[hhE][rowE][u][0]) = pk;
        }
    };

    // ---- compute-wave constants ----
    const int s_ = wid & 1;
    const int g_ = (wid >> 1) & 1;
    const int baseRow = 4 * s_;
    const int colBase = g_ * 32 + (lane & 31);
    const int chalfB  = lane >> 5;

    bf16x8 aP[3], aQ[3];
    {
        const bf16x8* ap = reinterpret_cast<const bf16x8*>(afrag + (size_t)bt * 6 * 64 * 8);
        #pragma unroll
        for (int C = 0; C < 3; ++C) {
            aP[C] = ap[C * 64 + lane];
            aQ[C] = ap[(3 + C) * 64 + lane];
        }
    }
    int   o_j[8];
    float bias_j[8];
    #pragma unroll
    for (int j = 0; j < 8; ++j) {
        o_j[j] = (j & 3) + 8 * (j >> 2) + 4 * chalfB;
        bias_j[j] = conv_bias[o_j[j]];
    }

    auto compute = [&](int t) {
        if (wid >= 4) return;
        const int ghBase = h0s + TH * t + 4 * s_;
        f32x16 zro;
        #pragma unroll
        for (int i = 0; i < 16; ++i) zro[i] = 0.f;
        f32x16 cacc[5];
        #pragma unroll
        for (int k = 0; k < 6; ++k) {
            bf16x8 bv0, bv1, bv2;
            {
                const unsigned short* rbase = &tile[chalfB][baseRow + k][0][0];
                const int c0 = colBase,     u0 = swz(c0);
                const int c1 = colBase + 1, u1 = swz(c1);
                const int c2 = colBase + 2, u2 = swz(c2);
                bv0 = *reinterpret_cast<const bf16x8*>(&rbase[u0 * 8]);
                bv1 = *reinterpret_cast<const bf16x8*>(&rbase[u1 * 8]);
                bv2 = *reinterpret_cast<const bf16x8*>(&rbase[u2 * 8]);
            }
            if (k <= 4) {   // P: births chain C_k (h0 -> out k, h1 -> out k-1)
                f32x16 t0 = __builtin_amdgcn_mfma_f32_32x32x16_bf16(aP[0], bv0, zro, 0, 0, 0);
                t0 = __builtin_amdgcn_mfma_f32_32x32x16_bf16(aP[1], bv1, t0, 0, 0, 0);
                t0 = __builtin_amdgcn_mfma_f32_32x32x16_bf16(aP[2], bv2, t0, 0, 0, 0);
                cacc[k] = t0;
            }
            if (k >= 2) {   // Q: finishes chain C_{k-2} (h0 -> out k-2), then emit
                f32x16 t1 = cacc[k - 2];
                t1 = __builtin_amdgcn_mfma_f32_32x32x16_bf16(aQ[0], bv0, t1, 0, 0, 0);
                t1 = __builtin_amdgcn_mfma_f32_32x32x16_bf16(aQ[1], bv1, t1, 0, 0, 0);
                t1 = __builtin_amdgcn_mfma_f32_32x32x16_bf16(aQ[2], bv2, t1, 0, 0, 0);
                cacc[k - 2] = t1;
                const int r = k - 2;
                const int gh = ghBase + r;
                const float noi = nb[(size_t)gh * W_ + w0 + colBase] * sn;
                #pragma unroll
                for (int j = 0; j < 8; ++j) {
                    float v = cacc[k - 2][j] + cacc[k - 1][8 + j] + bias_j[j] + noi;
                    v = (v >= 0.f) ? v : (LRELU * v);
                    yb[((size_t)o_j[j] * H_ + gh) * W_ + w0 + colBase] = v * GAIN_;
                }
            }
        }
    };

    // ---- persistent pipeline (prefetch t+1 across compute t) ----
    stage_load(0);
    for (int t = 0; t < NT; ++t) {
        if (t > 0) BAR_LGKM();           // readers of tile t-1 done (LDS WAR)
        stage_write();                    // compiler waits exact vmcnt for load(t)
        BAR_LGKM();                       // tile t visible (LDS RAW)
        if (t + 1 < NT) stage_load(t + 1);
        compute(t);
    }
}

extern "C" void kernel_launch(void* const* d_in, const int* in_sizes, int n_in,
                              void* d_out, int out_size, void* d_ws, size_t ws_size,
                              hipStream_t stream)
{
    const float* w     = (const float*)d_in[0];
    const float* x     = (const float*)d_in[1];
    const float* noise = (const float*)d_in[2];
    const float* fcw   = (const float*)d_in[3];
    const float* fcb   = (const float*)d_in[4];
    const float* convw = (const float*)d_in[5];
    const float* convb = (const float*)d_in[6];
    const float* sn    = (const float*)d_in[7];

    float* out = (float*)d_out;
    float* ws_s = (float*)d_ws;                                        // 64 f32
    unsigned short* ws_afrag = (unsigned short*)((char*)d_ws + 256);   // 4*3072 u16

    k_setup1<<<1, 256, 0, stream>>>(w, fcw, fcb, ws_s, out);
    k_setup2<<<B_, 256, 0, stream>>>(ws_s, convw, ws_afrag);
    dim3 grid(W_ / TW, H_ / (TH * NT), B_);
    k_conv<<<grid, 320, 0, stream>>>(x, noise, convb, sn, ws_afrag, out + 2048);
}

// Round 10
// 165.317 us; speedup vs baseline: 1.2151x; 1.0138x over previous
//
#include <hip/hip_runtime.h>

#define H_ 1024
#define W_ 1024
#define B_ 4
#define CIN 16
#define COUT 16
#define TH 8
#define TW 64
#define NT 16         // vertical tiles per persistent block (strip = 128 rows)
#define ROWS 10       // TH+2
#define COLS_U 74     // swizzled 16B-units per row: max u = 65 + (65>>3) = 73

#define LRELU 0.2f
#define GAIN_ 1.4142135623730951f
#define EPS_ 1e-8f

// LDS-only barrier (no vmcnt drain): prefetch loads/stores stay in flight.
#define BAR_LGKM()                                                      \
    do {                                                                \
        __builtin_amdgcn_sched_barrier(0);                              \
        asm volatile("s_waitcnt lgkmcnt(0)\n\ts_barrier" ::: "memory"); \
        __builtin_amdgcn_sched_barrier(0);                              \
    } while (0)

typedef __attribute__((ext_vector_type(8))) short bf16x8;
typedef __attribute__((ext_vector_type(16))) float f32x16;

static __device__ __forceinline__ unsigned short f32_to_bf16(float f) {
    unsigned int u = __float_as_uint(f);
    unsigned int r = u + 0x7FFF + ((u >> 16) & 1);   // RNE
    return (unsigned short)(r >> 16);
}

static __device__ __forceinline__ float f4c(const float4& v, int px) {
    return px == 0 ? v.x : px == 1 ? v.y : px == 2 ? v.z : v.w;
}

static __device__ __forceinline__ int swz(int c) { return c + (c >> 3); }

// ---------------- setup 1: s[b,i] = w @ (fcw.T * 512^-0.5) + bias; copy w to out ----
__global__ __launch_bounds__(256) void k_setup1(
    const float* __restrict__ w, const float* __restrict__ fcw,
    const float* __restrict__ fcb, float* __restrict__ s_out,
    float* __restrict__ w_copy_out)
{
    __shared__ float part[256];
    const int tid = threadIdx.x;
    const int bi = tid >> 2;   // 0..63 -> (b,i)
    const int q  = tid & 3;
    const int b = bi >> 4, i = bi & 15;
    const float* wr = w + b * 512 + q * 128;
    const float* fr = fcw + i * 512 + q * 128;
    float acc = 0.f;
    #pragma unroll 8
    for (int k = 0; k < 128; ++k) acc += wr[k] * fr[k];
    part[tid] = acc;
    __syncthreads();
    if (tid < 64) {
        float v = part[tid*4] + part[tid*4+1] + part[tid*4+2] + part[tid*4+3];
        s_out[tid] = v * 0.04419417382415922f /* 512^-0.5 */ + fcb[tid & 15];
    }
    for (int e = tid; e < B_ * 512; e += 256) w_copy_out[e] = w[e];
}

// ---------------- setup 2: d[b,o], W_eff -> 32x32x16 A-fragments (P/Q packed) -------
// frag f = 0..5: f<3 -> P(C=f): m-half R=0 -> tap C, R=1 -> tap 3+C
//               f>=3 -> Q(C=f-3): R=0 -> tap 6+C, R=1 -> zero
// A layout (32x32x16): lane l holds A[m=l&31][k=8*(l>>5)+j], j=0..7.
// m = R*16 + o  (R=(l>>4)&1, o=l&15), k = input channel i.
__global__ __launch_bounds__(256) void k_setup2(
    const float* __restrict__ s_in, const float* __restrict__ convw,
    unsigned short* __restrict__ afrag)
{
    const int b = blockIdx.x;
    const int tid = threadIdx.x;
    __shared__ float s_sh[16];
    __shared__ float d_sh[16];
    __shared__ float wc_sh[COUT * CIN * 9];
    __shared__ float part[256];

    if (tid < 16) s_sh[tid] = s_in[b * 16 + tid];
    for (int e = tid; e < COUT * CIN * 9; e += 256)
        wc_sh[e] = convw[e] * (1.0f / 12.0f);   // (16*9)^-0.5
    __syncthreads();

    const int o = tid >> 4, i = tid & 15;
    const float si = s_sh[i];
    float acc = 0.f;
    #pragma unroll
    for (int tap = 0; tap < 9; ++tap) {
        float v = wc_sh[(o * 16 + i) * 9 + tap] * si;
        acc += v * v;
    }
    part[tid] = acc;
    __syncthreads();
    if (tid < 16) {
        float sum = EPS_;
        #pragma unroll
        for (int j = 0; j < 16; ++j) sum += part[tid * 16 + j];
        d_sh[tid] = rsqrtf(sum);
    }
    __syncthreads();

    for (int e = tid; e < 6 * 64 * 8; e += 256) {
        const int f    = e >> 9;         // 0..5
        const int lane = (e >> 3) & 63;
        const int j    = e & 7;
        const int C    = (f < 3) ? f : (f - 3);
        const bool isQ = (f >= 3);
        const int oo = lane & 15;
        const int R  = (lane >> 4) & 1;
        const int ii = 8 * (lane >> 5) + j;
        int tap;
        if (!isQ) tap = 3 * R + C;                 // rows 0,1
        else      tap = (R == 0) ? (6 + C) : -1;   // row 2 / zero pad
        float v = 0.f;
        if (tap >= 0) v = wc_sh[(oo * 16 + ii) * 9 + tap] * s_sh[ii] * d_sh[oo];
        afrag[(size_t)b * (6 * 64 * 8) + e] = f32_to_bf16(v);
    }
}

// ---------------- main conv: 32x32x16 M-packed implicit GEMM -----------------------
// r9 structure + (a) noise prefetched into regs during staging, (b) in-place
// zero-init of born chains (3-slot rolling, no persistent zro), (c) setprio(1)
// around the MFMA sweep (staging wave stays prio 0).
__global__ __launch_bounds__(320) void k_conv(
    const float* __restrict__ x, const float* __restrict__ noise,
    const float* __restrict__ conv_bias, const float* __restrict__ sn_ptr,
    const unsigned short* __restrict__ afrag, float* __restrict__ y)
{
    __shared__ unsigned short tile[2][ROWS][COLS_U][8]; // 23680 B

    const int tid = threadIdx.x;
    const int bt = blockIdx.z;
    const int h0s = blockIdx.y * (TH * NT);
    const int w0 = blockIdx.x * TW;
    const float sn = sn_ptr[0];
    const float* xb = x + (size_t)bt * CIN * H_ * W_;
    float* yb = y + (size_t)bt * COUT * H_ * W_;
    const float* nb = noise + (size_t)bt * H_ * W_;

    const int lane = tid & 63;
    const int wid  = tid >> 6;           // 0..4

    // ---- staging roles ----
    const int rowS = tid >> 5;           // 0..9 (all 320 threads)
    const int subS = tid & 31;
    const int hhS  = subS >> 4;
    const int cgS  = subS & 15;
    const bool hasE = (tid >= 256) && (tid < 296);
    const int e_   = tid - 256;
    const int rowE = e_ >> 2, sideE = (e_ >> 1) & 1, hhE = e_ & 1;

    float4 vS[8];
    float  ev[8];
    float  nv[4];                        // prefetched noise (compute waves)

    auto stage_load = [&](int t) {
        const int gh0 = h0s + TH * t - 1;
        {
            const int gh = gh0 + rowS;
            const bool ok = (gh >= 0) && (gh < H_);
            const float* base = xb + ((size_t)(8 * hhS) * H_ + gh) * W_ + (w0 + 4 * cgS);
            #pragma unroll
            for (int c = 0; c < 8; ++c) {
                vS[c] = make_float4(0.f, 0.f, 0.f, 0.f);
                if (ok) vS[c] = *reinterpret_cast<const float4*>(base + (size_t)c * H_ * W_);
            }
        }
        if (hasE) {
            const int gh = gh0 + rowE;
            const int gw = w0 - 1 + sideE * 65;
            const bool ok = (gh >= 0) && (gh < H_) && (gw >= 0) && (gw < W_);
            #pragma unroll
            for (int c = 0; c < 8; ++c)
                ev[c] = ok ? xb[((size_t)(8 * hhE + c) * H_ + gh) * W_ + gw] : 0.f;
        }
    };

    // ---- compute-wave constants ----
    const int s_ = wid & 1;
    const int g_ = (wid >> 1) & 1;
    const int baseRow = 4 * s_;
    const int colBase = g_ * 32 + (lane & 31);
    const int chalfB  = lane >> 5;

    // issue noise loads for tile t early (hidden under staging/compute)
    auto noise_prefetch = [&](int t) {
        if (wid < 4) {
            const int ghB = h0s + TH * t + 4 * s_;
            #pragma unroll
            for (int r = 0; r < 4; ++r)
                nv[r] = nb[(size_t)(ghB + r) * W_ + w0 + colBase];
        }
    };

    auto stage_write = [&]() {
        #pragma unroll
        for (int px = 0; px < 4; ++px) {
            bf16x8 pk;
            #pragma unroll
            for (int c = 0; c < 8; ++c) pk[c] = (short)f32_to_bf16(f4c(vS[c], px));
            const int u = swz(1 + 4 * cgS + px);
            *reinterpret_cast<bf16x8*>(&tile[hhS][rowS][u][0]) = pk;
        }
        if (hasE) {
            bf16x8 pk;
            #pragma unroll
            for (int c = 0; c < 8; ++c) pk[c] = (short)f32_to_bf16(ev[c]);
            const int u = sideE ? swz(65) : 0;
            *reinterpret_cast<bf16x8*>(&tile[hhE][rowE][u][0]) = pk;
        }
    };

    bf16x8 aP[3], aQ[3];
    {
        const bf16x8* ap = reinterpret_cast<const bf16x8*>(afrag + (size_t)bt * 6 * 64 * 8);
        #pragma unroll
        for (int C = 0; C < 3; ++C) {
            aP[C] = ap[C * 64 + lane];
            aQ[C] = ap[(3 + C) * 64 + lane];
        }
    }
    int   o_j[8];
    float bias_j[8];
    #pragma unroll
    for (int j = 0; j < 8; ++j) {
        o_j[j] = (j & 3) + 8 * (j >> 2) + 4 * chalfB;
        bias_j[j] = conv_bias[o_j[j]];
    }

// One sweep row: born chain C_K (slot K%3), finish chain C_{K-2}, emit row K-2.
#define KROW(K, BORN, PREV, FIN)                                                     \
    {                                                                                \
        const unsigned short* rbase = &tile[chalfB][baseRow + (K)][0][0];            \
        bf16x8 bv0 = *reinterpret_cast<const bf16x8*>(&rbase[swz(colBase + 0) * 8]); \
        bf16x8 bv1 = *reinterpret_cast<const bf16x8*>(&rbase[swz(colBase + 1) * 8]); \
        bf16x8 bv2 = *reinterpret_cast<const bf16x8*>(&rbase[swz(colBase + 2) * 8]); \
        if ((K) <= 4) {                                                              \
            _Pragma("unroll")                                                        \
            for (int i_ = 0; i_ < 16; ++i_) BORN[i_] = 0.f;                          \
            BORN = __builtin_amdgcn_mfma_f32_32x32x16_bf16(aP[0], bv0, BORN, 0, 0, 0); \
            BORN = __builtin_amdgcn_mfma_f32_32x32x16_bf16(aP[1], bv1, BORN, 0, 0, 0); \
            BORN = __builtin_amdgcn_mfma_f32_32x32x16_bf16(aP[2], bv2, BORN, 0, 0, 0); \
        }                                                                            \
        if ((K) >= 2) {                                                              \
            FIN = __builtin_amdgcn_mfma_f32_32x32x16_bf16(aQ[0], bv0, FIN, 0, 0, 0); \
            FIN = __builtin_amdgcn_mfma_f32_32x32x16_bf16(aQ[1], bv1, FIN, 0, 0, 0); \
            FIN = __builtin_amdgcn_mfma_f32_32x32x16_bf16(aQ[2], bv2, FIN, 0, 0, 0); \
            const int r_ = (K) - 2;                                                  \
            const int gh_ = ghBase + r_;                                             \
            const float noi_ = nv[r_] * sn;                                          \
            _Pragma("unroll")                                                        \
            for (int j_ = 0; j_ < 8; ++j_) {                                         \
                float v_ = FIN[j_] + PREV[8 + j_] + bias_j[j_] + noi_;               \
                v_ = (v_ >= 0.f) ? v_ : (LRELU * v_);                                \
                yb[((size_t)o_j[j_] * H_ + gh_) * W_ + w0 + colBase] = v_ * GAIN_;   \
            }                                                                        \
        }                                                                            \
    }

    auto compute = [&](int t) {
        if (wid >= 4) return;
        const int ghBase = h0s + TH * t + 4 * s_;
        f32x16 c0, c1, c2;
        __builtin_amdgcn_s_setprio(1);
        KROW(0, c0, c2, c1);
        KROW(1, c1, c0, c2);
        KROW(2, c2, c1, c0);
        KROW(3, c0, c2, c1);
        KROW(4, c1, c0, c2);
        KROW(5, c2, c1, c0);
        __builtin_amdgcn_s_setprio(0);
    };

    // ---- persistent pipeline (prefetch t+1 across compute t) ----
    stage_load(0);
    for (int t = 0; t < NT; ++t) {
        if (t > 0) BAR_LGKM();           // readers of tile t-1 done (LDS WAR)
        noise_prefetch(t);                // noise for tile t in flight early
        stage_write();                    // compiler waits exact vmcnt for load(t)
        BAR_LGKM();                       // tile t visible (LDS RAW)
        if (t + 1 < NT) stage_load(t + 1);
        compute(t);
    }
}

extern "C" void kernel_launch(void* const* d_in, const int* in_sizes, int n_in,
                              void* d_out, int out_size, void* d_ws, size_t ws_size,
                              hipStream_t stream)
{
    const float* w     = (const float*)d_in[0];
    const float* x     = (const float*)d_in[1];
    const float* noise = (const float*)d_in[2];
    const float* fcw   = (const float*)d_in[3];
    const float* fcb   = (const float*)d_in[4];
    const float* convw = (const float*)d_in[5];
    const float* convb = (const float*)d_in[6];
    const float* sn    = (const float*)d_in[7];

    float* out = (float*)d_out;
    float* ws_s = (float*)d_ws;                                        // 64 f32
    unsigned short* ws_afrag = (unsigned short*)((char*)d_ws + 256);   // 4*3072 u16

    k_setup1<<<1, 256, 0, stream>>>(w, fcw, fcb, ws_s, out);
    k_setup2<<<B_, 256, 0, stream>>>(ws_s, convw, ws_afrag);
    dim3 grid(W_ / TW, H_ / (TH * NT), B_);
    k_conv<<<grid, 320, 0, stream>>>(x, noise, convb, sn, ws_afrag, out + 2048);
}